// Round 4
// baseline (264.749 us; speedup 1.0000x reference)
//
#include <hip/hip_runtime.h>
#include <hip/hip_bf16.h>
#include <stdint.h>

typedef __bf16 bf16;
typedef __bf16 bf16x8 __attribute__((ext_vector_type(8)));
typedef float  f32x4  __attribute__((ext_vector_type(4)));

#define E  512
#define SB 4112            // per-batch extended row stride (4098 valid + 14 pad)
#define M1 (8 * SB)        // 32896 = 128 * 257 extended rows
#define M2 32768           // output rows
#define NT 16              // K tiles of 32

__device__ __forceinline__ void gl_lds_16(const bf16* g, bf16* l) {
    __builtin_amdgcn_global_load_lds(
        (__attribute__((address_space(1))) void*)g,
        (__attribute__((address_space(3))) void*)l,
        16, 0, 0);
}

// LDS tile layout (per 128x32 bf16 matrix): slot(row,ch) = (row>>4)*64 + ch*16
// + (row&15), each slot 16B (8 bf16, k = ch*8..ch*8+7).  Staged via gl_lds with
// linear LDS dest (slot = call*256 + tid) and the PERMUTED per-lane global
// source; fragment ds_read_b128 (16 consecutive rows, fixed ch) is then 256B
// contiguous -> uniform 8 words/bank, conflict-free.  Global side: each wave
// covers 16 full 64B rows per call -> fully-consumed cache lines.
//
// Schedule: 3-buffer ring, distance-2 prefetch, counted vmcnt (4 loads/thread
// per tile), raw s_barrier.  iter t: stage T(t+2) -> ring[(t+2)%3]; compute
// ring[t%3]; s_waitcnt vmcnt(4) (T(t+1) retired, T(t+2) in flight); s_barrier.
// WAR: ring[(t+2)%3] last read at iter t-1, behind that barrier.  Tail: vmcnt(0)
// at t==NT-2 (no more stages in flight to hide behind).

// ---------------- GEMM1: C[m,n] = sum_k A[m,k]*B[n,k], bf16 out ----------------
__global__ __launch_bounds__(256, 3)
void gemm_bt_bf16(const bf16* __restrict__ A, const bf16* __restrict__ Bm,
                  bf16* __restrict__ C, int M, int N, int K)
{
    __shared__ bf16 ring[3][8192];        // per buf: A[0:4096), B[4096:8192)

    const int tid  = threadIdx.x;
    const int id   = blockIdx.x;          // 1D grid, bn fastest
    const int bm   = id >> 2;
    const int bn   = id & 3;
    const int wave = tid >> 6;
    const int lane = tid & 63;
    const int wm   = wave >> 1;
    const int wn   = wave & 1;

    // staging coords: slot s = c*256+tid -> rb=s>>6, ch=(s>>4)&3, rw=s&15
    const int gr0  = ((tid >> 6) << 4) + (tid & 15);   // row for call 0
    const int gcol = ((tid >> 4) & 3) << 3;            // k-offset (elems)
    const size_t a_base = (size_t)(bm * 128 + gr0) * K + gcol;
    const size_t b_base = (size_t)(bn * 128 + gr0) * K + gcol;

    f32x4 acc[4][4] = {};
    const int fr = lane & 15;
    const int q  = lane >> 4;             // chunk = k/8

    auto stage = [&](int t, int p) {
        const size_t gk = (size_t)t << 5;
        bf16* buf = ring[p];
        gl_lds_16(A  + a_base + gk,                  buf + tid * 8);
        gl_lds_16(A  + a_base + (size_t)64 * K + gk, buf + (256 + tid) * 8);
        gl_lds_16(Bm + b_base + gk,                  buf + 4096 + tid * 8);
        gl_lds_16(Bm + b_base + (size_t)64 * K + gk, buf + 4096 + (256 + tid) * 8);
    };

    stage(0, 0);
    stage(1, 1);
    __asm__ volatile("s_waitcnt vmcnt(4)" ::: "memory");   // T0 retired
    __asm__ volatile("s_barrier" ::: "memory");

#pragma unroll
    for (int t = 0; t < NT; ++t) {
        if (t + 2 < NT) stage(t + 2, (t + 2) % 3);

        const bf16* Ab = ring[t % 3];
        const bf16* Bb = ring[t % 3] + 4096;
        bf16x8 af[4], bfv[4];
#pragma unroll
        for (int i = 0; i < 4; ++i) {
            af[i]  = *(const bf16x8*)(Ab + (((wm * 4 + i) * 64) + q * 16 + fr) * 8);
            bfv[i] = *(const bf16x8*)(Bb + (((wn * 4 + i) * 64) + q * 16 + fr) * 8);
        }
#pragma unroll
        for (int i = 0; i < 4; ++i)
#pragma unroll
            for (int j = 0; j < 4; ++j)
                acc[i][j] = __builtin_amdgcn_mfma_f32_16x16x32_bf16(af[i], bfv[j], acc[i][j], 0, 0, 0);

        if (t < NT - 2)      __asm__ volatile("s_waitcnt vmcnt(4)" ::: "memory");
        else if (t == NT - 2) __asm__ volatile("s_waitcnt vmcnt(0)" ::: "memory");
        if (t < NT - 1)      __asm__ volatile("s_barrier" ::: "memory");
    }

    const int crow = (lane >> 4) << 2;
    const int ccol = lane & 15;
    const int row0 = bm * 128 + wm * 64 + crow;
    const int col0 = bn * 128 + wn * 64 + ccol;
#pragma unroll
    for (int i = 0; i < 4; ++i)
#pragma unroll
        for (int j = 0; j < 4; ++j)
#pragma unroll
            for (int r = 0; r < 4; ++r)
                C[(size_t)(row0 + i * 16 + r) * N + (col0 + j * 16)] = (bf16)acc[i][j][r];
}

// ------- GEMM2: A gathered with per-head row shift; fp32 out ------------------
// A2[m=(b,s), k] = P[b*SB + s + 1 + sh(head(k))], head = k>>6; tile t covers
// k in [t*32, t*32+32) -> head = t>>1, wave-uniform per staged tile.
__global__ __launch_bounds__(256, 3)
void gemm2_gather(const bf16* __restrict__ P, const bf16* __restrict__ Bm,
                  float* __restrict__ C)
{
    __shared__ bf16 ring[3][8192];

    const int tid  = threadIdx.x;
    const int id   = blockIdx.x;
    const int bm   = id >> 2;
    const int bn   = id & 3;
    const int wave = tid >> 6;
    const int lane = tid & 63;
    const int wm   = wave >> 1;
    const int wn   = wave & 1;

    const int gr0  = ((tid >> 6) << 4) + (tid & 15);
    const int gcol = ((tid >> 4) & 3) << 3;
    const int m0   = bm * 128 + gr0;                   // call-0 output row
    const int pr0  = (m0 >> 12) * SB + (m0 & 4095) + 1;
    const int m1   = m0 + 64;                          // call-1 output row
    const int pr1  = (m1 >> 12) * SB + (m1 & 4095) + 1;
    const size_t b_base = (size_t)(bn * 128 + gr0) * E + gcol;

    f32x4 acc[4][4] = {};
    const int fr = lane & 15;
    const int q  = lane >> 4;

    auto stage = [&](int t, int p) {
        const size_t gk = (size_t)t << 5;
        const int h3 = (t >> 1) & 3;
        const int sh = (h3 == 1) ? -1 : (h3 == 2) ? 1 : 0;   // wave-uniform
        bf16* buf = ring[p];
        gl_lds_16(P  + (size_t)(pr0 + sh) * E + gcol + gk,   buf + tid * 8);
        gl_lds_16(P  + (size_t)(pr1 + sh) * E + gcol + gk,   buf + (256 + tid) * 8);
        gl_lds_16(Bm + b_base + gk,                          buf + 4096 + tid * 8);
        gl_lds_16(Bm + b_base + (size_t)64 * E + gk,         buf + 4096 + (256 + tid) * 8);
    };

    stage(0, 0);
    stage(1, 1);
    __asm__ volatile("s_waitcnt vmcnt(4)" ::: "memory");
    __asm__ volatile("s_barrier" ::: "memory");

#pragma unroll
    for (int t = 0; t < NT; ++t) {
        if (t + 2 < NT) stage(t + 2, (t + 2) % 3);

        const bf16* Ab = ring[t % 3];
        const bf16* Bb = ring[t % 3] + 4096;
        bf16x8 af[4], bfv[4];
#pragma unroll
        for (int i = 0; i < 4; ++i) {
            af[i]  = *(const bf16x8*)(Ab + (((wm * 4 + i) * 64) + q * 16 + fr) * 8);
            bfv[i] = *(const bf16x8*)(Bb + (((wn * 4 + i) * 64) + q * 16 + fr) * 8);
        }
#pragma unroll
        for (int i = 0; i < 4; ++i)
#pragma unroll
            for (int j = 0; j < 4; ++j)
                acc[i][j] = __builtin_amdgcn_mfma_f32_16x16x32_bf16(af[i], bfv[j], acc[i][j], 0, 0, 0);

        if (t < NT - 2)      __asm__ volatile("s_waitcnt vmcnt(4)" ::: "memory");
        else if (t == NT - 2) __asm__ volatile("s_waitcnt vmcnt(0)" ::: "memory");
        if (t < NT - 1)      __asm__ volatile("s_barrier" ::: "memory");
    }

    const int crow = (lane >> 4) << 2;
    const int ccol = lane & 15;
    const int row0 = bm * 128 + wm * 64 + crow;
    const int col0 = bn * 128 + wn * 64 + ccol;
#pragma unroll
    for (int i = 0; i < 4; ++i)
#pragma unroll
        for (int j = 0; j < 4; ++j)
#pragma unroll
            for (int r = 0; r < 4; ++r)
                C[(size_t)(row0 + i * 16 + r) * E + (col0 + j * 16)] = acc[i][j][r];
}

// ------- prep: weight-convert blocks [0,256) + prefilter blocks [256,1284) ----
__global__ __launch_bounds__(256)
void prep(const float* __restrict__ vals, const float* __restrict__ w_in,
          const float* __restrict__ w_out, bf16* __restrict__ vg,
          bf16* __restrict__ win_b, bf16* __restrict__ wout_b)
{
    const int tid = threadIdx.x;
    const int blk = blockIdx.x;

    if (blk < 256) {                                   // weight convert
        const int i = blk * 256 + tid;                 // [0, 65536)
        const int half = (E * E) / 8;                  // 32768
        const float* src = (i < half) ? w_in : w_out;
        bf16* dst        = (i < half) ? win_b : wout_b;
        const int k = (i < half) ? i : i - half;
        const f32x4* p = (const f32x4*)src + 2 * (size_t)k;
        f32x4 a = p[0], bq = p[1];
        bf16x8 o;
        o[0] = (bf16)a[0];  o[1] = (bf16)a[1];  o[2] = (bf16)a[2];  o[3] = (bf16)a[3];
        o[4] = (bf16)bq[0]; o[5] = (bf16)bq[1]; o[6] = (bf16)bq[2]; o[7] = (bf16)bq[3];
        *((bf16x8*)dst + k) = o;
        return;
    }

    const int e8   = tid & 63;                         // channel chunk (8 floats)
    const int gidx = (blk - 256) * 4 + (tid >> 6);     // row group [0, M1/8)
    const int m0   = gidx << 3;                        // first extended row
    const int b    = m0 / SB;                          // group never straddles batch
    const int r0   = m0 - b * SB;                      // [0, 4112)

    const float filt[5] = {0.05399096651318806f, 0.24197072451914337f,
                           0.3989422804014327f,
                           0.24197072451914337f, 0.05399096651318806f};

    float acc[8][8];
#pragma unroll
    for (int t = 0; t < 8; ++t)
#pragma unroll
        for (int d = 0; d < 8; ++d) acc[t][d] = 0.f;

    const float* bbase = vals + (size_t)b * 4096 * E + e8 * 8;
#pragma unroll
    for (int u = 0; u < 12; ++u) {                     // inputs sp = r0-3 .. r0+8
        const int sp = r0 - 3 + u;
        if (sp >= 0 && sp < 4096) {
            const f32x4* p = (const f32x4*)(bbase + (size_t)sp * E);
            const f32x4 x0 = p[0], x1 = p[1];
            const float x[8] = {x0[0], x0[1], x0[2], x0[3],
                                x1[0], x1[1], x1[2], x1[3]};
#pragma unroll
            for (int t = 0; t < 8; ++t) {              // out row r0+t needs j = u-t
                const int j = u - t;
                if (j >= 0 && j < 5) {
                    const float w = filt[j];
#pragma unroll
                    for (int d = 0; d < 8; ++d) acc[t][d] += w * x[d];
                }
            }
        }
    }
#pragma unroll
    for (int t = 0; t < 8; ++t) {
        bf16x8 o;
#pragma unroll
        for (int d = 0; d < 8; ++d) o[d] = (bf16)acc[t][d];
        *((bf16x8*)vg + (size_t)(m0 + t) * 64 + e8) = o;
    }
}

extern "C" void kernel_launch(void* const* d_in, const int* in_sizes, int n_in,
                              void* d_out, int out_size, void* d_ws, size_t ws_size,
                              hipStream_t stream)
{
    const float* values = (const float*)d_in[0];
    // d_in[1]=keys, d_in[2]=queries: unused by the reference path (no QK^T)
    const float* w_in   = (const float*)d_in[3];
    const float* w_out  = (const float*)d_in[4];
    float* out = (float*)d_out;

    // workspace: weights 1 MB + VG 33.7 MB + P 33.7 MB ~= 68.4 MB
    bf16* win_b  = (bf16*)d_ws;                 // 512*512
    bf16* wout_b = win_b + E * E;               // 512*512
    bf16* vg     = wout_b + E * E;              // M1*E
    bf16* Pbuf   = vg + (size_t)M1 * E;         // M1*E

    prep<<<256 + M1 / 32, 256, 0, stream>>>(values, w_in, w_out, vg, win_b, wout_b);

    // 1D grids, bn fastest: the 4 column-blocks sharing an A-panel run adjacently
    gemm_bt_bf16<<<(M1 / 128) * 4, 256, 0, stream>>>(vg, win_b, Pbuf, M1, E, E);
    gemm2_gather<<<(M2 / 128) * 4, 256, 0, stream>>>(Pbuf, wout_b, out);
}

// Round 5
// 231.966 us; speedup vs baseline: 1.1413x; 1.1413x over previous
//
#include <hip/hip_runtime.h>
#include <hip/hip_bf16.h>
#include <stdint.h>

typedef __bf16 bf16;
typedef __bf16 bf16x8 __attribute__((ext_vector_type(8)));
typedef float  f32x4  __attribute__((ext_vector_type(4)));

#define BM 128
#define BN 64
#define BK 64
#define E  512
#define SB 4112            // per-batch extended row stride (4098 valid + 14 pad)
#define M1 (8 * SB)        // 32896 = 128 * 257 extended rows
#define M2 32768           // output rows

__device__ __forceinline__ void gl_lds_16(const bf16* g, bf16* l) {
    __builtin_amdgcn_global_load_lds(
        (__attribute__((address_space(1))) void*)g,
        (__attribute__((address_space(3))) void*)l,
        16, 0, 0);
}

// Structure notes (measured across rounds 0-4):
//  - 2-phase stage->sync->compute->sync at 128-row tiles is the best-measured
//    form (round 1).  Counted-vmcnt rings (r4) and 256^2 deep-cover (r2) both
//    REGRESSED ~70%: these kernels are latency-bound and live off TLP, which
//    schedule surgery reduced (matches guide m131-m141 nulls).
//  - This round: BN=64 -> 24KB LDS -> 6 resident blocks/CU (was 4) for more
//    TLP, plus XCD-grouping block swizzle so all 8 bn-siblings of an A-panel
//    share one XCD L2 (grids 2056/2048 are 8-divisible -> clean bijection).
//  - XOR chunk swizzle on LDS (linear gl_lds dest + pre-swizzled global col +
//    swizzled ds_read) keeps fragment reads 2-way-conflict-free (free, m136).

// ---------------- GEMM1: C[m,n] = sum_k A[m,k]*B[n,k], bf16 out ----------------
__global__ __launch_bounds__(256)
void gemm_bt_bf16(const bf16* __restrict__ A, const bf16* __restrict__ Bm,
                  bf16* __restrict__ C, int M, int N, int K)
{
    __shared__ bf16 As[BM * BK];          // 16 KB
    __shared__ bf16 Bs[BN * BK];          // 8 KB

    const int tid  = threadIdx.x;
    // XCD-grouping: HW assigns xcd ~ bid%8; give each XCD a contiguous run of
    // original ids so the 8 bn-siblings of each bm stay on one L2.
    const int nq   = gridDim.x >> 3;                  // 2056/8 = 257
    const int orig = (blockIdx.x & 7) * nq + (blockIdx.x >> 3);
    const int bm   = orig >> 3;                       // 0..256
    const int bn   = orig & 7;                        // 0..7
    const int wave = tid >> 6;
    const int lane = tid & 63;
    const int wm   = wave >> 1;                       // 0..1 (64 rows)
    const int wn   = wave & 1;                        // 0..1 (32 cols)

    const int srow = tid >> 3;                        // 0..31
    const int scol = (((tid & 7) ^ (srow & 7)) << 3); // swizzled source col
    const size_t a_off = (size_t)(bm * BM + srow) * K + scol;
    const size_t b_off = (size_t)(bn * BN + srow) * K + scol;
    const int    l_off = tid * 8;                     // linear dest: lane*16B

    f32x4 acc[4][2] = {};
    const int fr = lane & 15;
    const int q  = lane >> 4;

    for (int k0 = 0; k0 < K; k0 += BK) {
#pragma unroll
        for (int c = 0; c < 4; ++c)                   // A: 4 calls x 32 rows
            gl_lds_16(A + a_off + (size_t)(c * 32) * K + k0, As + c * 2048 + l_off);
#pragma unroll
        for (int c = 0; c < 2; ++c)                   // B: 2 calls x 32 rows
            gl_lds_16(Bm + b_off + (size_t)(c * 32) * K + k0, Bs + c * 2048 + l_off);
        __syncthreads();

#pragma unroll
        for (int t = 0; t < 2; ++t) {                 // two 32-wide k sub-steps
            bf16x8 af[4], bfr[2];
#pragma unroll
            for (int i = 0; i < 4; ++i) {
                const int Ra = wm * 64 + i * 16 + fr;
                const int c  = t * 4 + q;
                af[i] = *(const bf16x8*)(As + Ra * BK + ((c ^ (Ra & 7)) << 3));
            }
#pragma unroll
            for (int j = 0; j < 2; ++j) {
                const int Rb = wn * 32 + j * 16 + fr;
                const int c  = t * 4 + q;
                bfr[j] = *(const bf16x8*)(Bs + Rb * BK + ((c ^ (Rb & 7)) << 3));
            }
#pragma unroll
            for (int i = 0; i < 4; ++i)
#pragma unroll
                for (int j = 0; j < 2; ++j)
                    acc[i][j] = __builtin_amdgcn_mfma_f32_16x16x32_bf16(af[i], bfr[j], acc[i][j], 0, 0, 0);
        }
        __syncthreads();
    }

    const int crow = (lane >> 4) << 2;
    const int ccol = lane & 15;
    const int row0 = bm * BM + wm * 64 + crow;
    const int col0 = bn * BN + wn * 32 + ccol;
#pragma unroll
    for (int i = 0; i < 4; ++i)
#pragma unroll
        for (int j = 0; j < 2; ++j)
#pragma unroll
            for (int r = 0; r < 4; ++r)
                C[(size_t)(row0 + i * 16 + r) * N + (col0 + j * 16)] = (bf16)acc[i][j][r];
}

// ------- GEMM2: A gathered with per-head row shift; fp32 out ------------------
// A2[m=(b,s), k] = P[b*SB + s + 1 + sh(k>>6), k]; sh uniform per K-iter
// (BK=64 == one head).  Same BN=64 + XCD swizzle treatment as GEMM1.
__global__ __launch_bounds__(256)
void gemm2_gather(const bf16* __restrict__ P, const bf16* __restrict__ Bm,
                  float* __restrict__ C)
{
    __shared__ bf16 As[BM * BK];
    __shared__ bf16 Bs[BN * BK];

    const int tid  = threadIdx.x;
    const int nq   = gridDim.x >> 3;                  // 2048/8 = 256
    const int orig = (blockIdx.x & 7) * nq + (blockIdx.x >> 3);
    const int bm   = orig >> 3;                       // 0..255
    const int bn   = orig & 7;                        // 0..7
    const int wave = tid >> 6;
    const int lane = tid & 63;
    const int wm   = wave >> 1;
    const int wn   = wave & 1;

    const int srow = tid >> 3;                        // 0..31
    const int scol = (((tid & 7) ^ (srow & 7)) << 3);
    const size_t b_off = (size_t)(bn * BN + srow) * E + scol;
    const int    l_off = tid * 8;

    f32x4 acc[4][2] = {};
    const int fr = lane & 15;
    const int q  = lane >> 4;

    for (int k0 = 0; k0 < E; k0 += BK) {
        const int h3 = (k0 >> 6) & 3;                       // head pattern %4
        const int sh = (h3 == 1) ? -1 : (h3 == 2) ? 1 : 0;  // wave-uniform
#pragma unroll
        for (int c = 0; c < 4; ++c) {
            const int m = bm * BM + c * 32 + srow;          // output row staged
            const int prow = (m >> 12) * SB + (m & 4095) + 1 + sh;
            gl_lds_16(P + (size_t)prow * E + k0 + scol, As + c * 2048 + l_off);
        }
#pragma unroll
        for (int c = 0; c < 2; ++c)
            gl_lds_16(Bm + b_off + (size_t)(c * 32) * E + k0, Bs + c * 2048 + l_off);
        __syncthreads();

#pragma unroll
        for (int t = 0; t < 2; ++t) {
            bf16x8 af[4], bfr[2];
#pragma unroll
            for (int i = 0; i < 4; ++i) {
                const int Ra = wm * 64 + i * 16 + fr;
                const int c  = t * 4 + q;
                af[i] = *(const bf16x8*)(As + Ra * BK + ((c ^ (Ra & 7)) << 3));
            }
#pragma unroll
            for (int j = 0; j < 2; ++j) {
                const int Rb = wn * 32 + j * 16 + fr;
                const int c  = t * 4 + q;
                bfr[j] = *(const bf16x8*)(Bs + Rb * BK + ((c ^ (Rb & 7)) << 3));
            }
#pragma unroll
            for (int i = 0; i < 4; ++i)
#pragma unroll
                for (int j = 0; j < 2; ++j)
                    acc[i][j] = __builtin_amdgcn_mfma_f32_16x16x32_bf16(af[i], bfr[j], acc[i][j], 0, 0, 0);
        }
        __syncthreads();
    }

    const int crow = (lane >> 4) << 2;
    const int ccol = lane & 15;
    const int row0 = bm * BM + wm * 64 + crow;
    const int col0 = bn * BN + wn * 32 + ccol;
#pragma unroll
    for (int i = 0; i < 4; ++i)
#pragma unroll
        for (int j = 0; j < 2; ++j)
#pragma unroll
            for (int r = 0; r < 4; ++r)
                C[(size_t)(row0 + i * 16 + r) * E + (col0 + j * 16)] = acc[i][j][r];
}

// ------- prep: weight-convert blocks [0,256) + prefilter blocks [256,1284) ----
// prefilter: VG[b, r, e] = sum_j filt[j] * values[b, r-1+j-2, e], 8 rows/thread
// sliding window (1.5x re-read).  cvt: both 512x512 fp32 -> bf16.
__global__ __launch_bounds__(256)
void prep(const float* __restrict__ vals, const float* __restrict__ w_in,
          const float* __restrict__ w_out, bf16* __restrict__ vg,
          bf16* __restrict__ win_b, bf16* __restrict__ wout_b)
{
    const int tid = threadIdx.x;
    const int blk = blockIdx.x;

    if (blk < 256) {                                   // weight convert
        const int i = blk * 256 + tid;                 // [0, 65536)
        const int half = (E * E) / 8;                  // 32768
        const float* src = (i < half) ? w_in : w_out;
        bf16* dst        = (i < half) ? win_b : wout_b;
        const int k = (i < half) ? i : i - half;
        const f32x4* p = (const f32x4*)src + 2 * (size_t)k;
        f32x4 a = p[0], bq = p[1];
        bf16x8 o;
        o[0] = (bf16)a[0];  o[1] = (bf16)a[1];  o[2] = (bf16)a[2];  o[3] = (bf16)a[3];
        o[4] = (bf16)bq[0]; o[5] = (bf16)bq[1]; o[6] = (bf16)bq[2]; o[7] = (bf16)bq[3];
        *((bf16x8*)dst + k) = o;
        return;
    }

    const int e8   = tid & 63;                         // channel chunk (8 floats)
    const int gidx = (blk - 256) * 4 + (tid >> 6);     // row group [0, M1/8)
    const int m0   = gidx << 3;                        // first extended row
    const int b    = m0 / SB;                          // group never straddles batch
    const int r0   = m0 - b * SB;                      // [0, 4112)

    const float filt[5] = {0.05399096651318806f, 0.24197072451914337f,
                           0.3989422804014327f,
                           0.24197072451914337f, 0.05399096651318806f};

    float acc[8][8];
#pragma unroll
    for (int t = 0; t < 8; ++t)
#pragma unroll
        for (int d = 0; d < 8; ++d) acc[t][d] = 0.f;

    const float* bbase = vals + (size_t)b * 4096 * E + e8 * 8;
#pragma unroll
    for (int u = 0; u < 12; ++u) {                     // inputs sp = r0-3 .. r0+8
        const int sp = r0 - 3 + u;
        if (sp >= 0 && sp < 4096) {
            const f32x4* p = (const f32x4*)(bbase + (size_t)sp * E);
            const f32x4 x0 = p[0], x1 = p[1];
            const float x[8] = {x0[0], x0[1], x0[2], x0[3],
                                x1[0], x1[1], x1[2], x1[3]};
#pragma unroll
            for (int t = 0; t < 8; ++t) {              // out row r0+t needs j = u-t
                const int j = u - t;
                if (j >= 0 && j < 5) {
                    const float w = filt[j];
#pragma unroll
                    for (int d = 0; d < 8; ++d) acc[t][d] += w * x[d];
                }
            }
        }
    }
#pragma unroll
    for (int t = 0; t < 8; ++t) {
        bf16x8 o;
#pragma unroll
        for (int d = 0; d < 8; ++d) o[d] = (bf16)acc[t][d];
        *((bf16x8*)vg + (size_t)(m0 + t) * 64 + e8) = o;
    }
}

extern "C" void kernel_launch(void* const* d_in, const int* in_sizes, int n_in,
                              void* d_out, int out_size, void* d_ws, size_t ws_size,
                              hipStream_t stream)
{
    const float* values = (const float*)d_in[0];
    // d_in[1]=keys, d_in[2]=queries: unused by the reference path (no QK^T)
    const float* w_in   = (const float*)d_in[3];
    const float* w_out  = (const float*)d_in[4];
    float* out = (float*)d_out;

    // workspace: weights 1 MB + VG 33.7 MB + P 33.7 MB ~= 68.4 MB
    bf16* win_b  = (bf16*)d_ws;                 // 512*512
    bf16* wout_b = win_b + E * E;               // 512*512
    bf16* vg     = wout_b + E * E;              // M1*E
    bf16* Pbuf   = vg + (size_t)M1 * E;         // M1*E

    prep<<<256 + M1 / 32, 256, 0, stream>>>(values, w_in, w_out, vg, win_b, wout_b);

    // grids: (M/128) x 8 column-blocks, 8-divisible -> clean XCD grouping
    gemm_bt_bf16<<<(M1 / BM) * 8, 256, 0, stream>>>(vg, win_b, Pbuf, M1, E, E);
    gemm2_gather<<<(M2 / BM) * 8, 256, 0, stream>>>(Pbuf, wout_b, out);
}